// Round 2
// baseline (514.819 us; speedup 1.0000x reference)
//
#include <hip/hip_runtime.h>
#include <math.h>

#define NH      16
#define D_NOPE  128
#define D_ROPE  64
#define D_QK    192
#define D_V     128
#define KV_LORA 512
#define NB      2
#define SEQ     2048
#define NTOK    (NB*SEQ)          // 4096
#define QROW    (NH*D_QK)         // 3072
#define KVBROW  (NH*(D_NOPE+D_V)) // 4096
#define EPSF    1e-6f

typedef unsigned short u16;
typedef float  floatx4 __attribute__((ext_vector_type(4)));
typedef __bf16 bf16x8  __attribute__((ext_vector_type(8)));
typedef u16    u16x4   __attribute__((ext_vector_type(4)));
typedef u16    u16x8   __attribute__((ext_vector_type(8)));

__device__ __forceinline__ u16 f2bf(float f) {
    unsigned u = __builtin_bit_cast(unsigned, f);
    return (u16)((u + 0x7fffu + ((u >> 16) & 1u)) >> 16);
}

__device__ __forceinline__ void async_copy16(const void* g, void* l) {
    __builtin_amdgcn_global_load_lds(
        (const __attribute__((address_space(1))) unsigned int*)g,
        (__attribute__((address_space(3))) unsigned int*)l,
        16, 0, 0);
}

// ---------------------------------------------------------------------------
// Fused fp32->bf16 cast of all 5 weight/activation arrays in ONE dispatch.
// ---------------------------------------------------------------------------
__global__ __launch_bounds__(256) void cast_all(const float* __restrict__ x,
                                                const float* __restrict__ wq,
                                                const float* __restrict__ wkva,
                                                const float* __restrict__ wkvb,
                                                const float* __restrict__ wo,
                                                u16* __restrict__ xb,
                                                u16* __restrict__ wqb,
                                                u16* __restrict__ wkvab,
                                                u16* __restrict__ wkvbb,
                                                u16* __restrict__ wob) {
    int blk = blockIdx.x;
    const float* src; u16* dst; bool pad = false;
    if (blk < 8192)        { src = x;    dst = xb; }
    else if (blk < 14336)  { blk -= 8192;  src = wq;   dst = wqb; }
    else if (blk < 15616)  { blk -= 14336; src = wkva; dst = wkvab; pad = true; }
    else if (blk < 17664)  { blk -= 15616; src = wkvb; dst = wkvbb; }
    else                   { blk -= 17664; src = wo;   dst = wob; }
    const int i = (blk * 256 + threadIdx.x) * 4;
    u16x4 o;
    if (pad && (i >> 11) >= 576) {
        o[0] = 0; o[1] = 0; o[2] = 0; o[3] = 0;
    } else {
        const float4 v = *(const float4*)&src[i];
        o[0] = f2bf(v.x); o[1] = f2bf(v.y); o[2] = f2bf(v.z); o[3] = f2bf(v.w);
    }
    *(u16x4*)&dst[i] = o;
}

// ---------------------------------------------------------------------------
// bf16 NT MFMA GEMM (m97 recipe), templated epilogue:
//   MODE 0: fp32 C[M,N] | MODE 1: bf16 C[M,N] | MODE 2: kv-split kbuf/vT.
// ---------------------------------------------------------------------------
template<int MODE>
__global__ __launch_bounds__(256) void gemm_mfma(const u16* __restrict__ A,
                                                 const u16* __restrict__ B,
                                                 void* __restrict__ Cout,
                                                 u16* __restrict__ kbuf,
                                                 u16* __restrict__ vT,
                                                 int M, int N, int K) {
    __shared__ u16 As[128 * 32];
    __shared__ u16 Bs[128 * 32];
    const int tid  = threadIdx.x;
    const int wave = tid >> 6, lane = tid & 63;
    const int m0 = blockIdx.y * 128, n0 = blockIdx.x * 128;
    const int wm = (wave & 1) * 64, wn = (wave >> 1) * 64;

    const int srow = wave * 32 + (lane >> 2);
    const int kch  = (lane & 3) * 8;
    const u16* gA0 = A + (size_t)(m0 + srow) * K + kch;
    const u16* gA1 = gA0 + (size_t)16 * K;
    const u16* gB0 = B + (size_t)(n0 + srow) * K + kch;
    const u16* gB1 = gB0 + (size_t)16 * K;
    u16* lA0 = &As[(wave * 32) * 32];
    u16* lA1 = &As[(wave * 32 + 16) * 32];
    u16* lB0 = &Bs[(wave * 32) * 32];
    u16* lB1 = &Bs[(wave * 32 + 16) * 32];

    floatx4 acc[4][4];
#pragma unroll
    for (int i = 0; i < 4; ++i)
#pragma unroll
        for (int j = 0; j < 4; ++j) acc[i][j] = 0.f;

    const int lrow = lane & 15;
    const int lkh  = (lane >> 4) * 8;

    for (int k0 = 0; k0 < K; k0 += 32) {
        __syncthreads();
        async_copy16(gA0 + k0, lA0);
        async_copy16(gA1 + k0, lA1);
        async_copy16(gB0 + k0, lB0);
        async_copy16(gB1 + k0, lB1);
        __syncthreads();
        bf16x8 a[4], b[4];
#pragma unroll
        for (int mi = 0; mi < 4; ++mi)
            a[mi] = *(const bf16x8*)&As[(wm + mi * 16 + lrow) * 32 + lkh];
#pragma unroll
        for (int ni = 0; ni < 4; ++ni)
            b[ni] = *(const bf16x8*)&Bs[(wn + ni * 16 + lrow) * 32 + lkh];
#pragma unroll
        for (int mi = 0; mi < 4; ++mi)
#pragma unroll
            for (int ni = 0; ni < 4; ++ni)
                acc[mi][ni] = __builtin_amdgcn_mfma_f32_16x16x32_bf16(
                    a[mi], b[ni], acc[mi][ni], 0, 0, 0);
    }

    const int crow = (lane >> 4) * 4, ccol = lane & 15;
#pragma unroll
    for (int mi = 0; mi < 4; ++mi)
#pragma unroll
        for (int ni = 0; ni < 4; ++ni) {
            const int m = m0 + wm + mi * 16 + crow;
            const int c = n0 + wn + ni * 16 + ccol;
            if (MODE == 0) {
                float* cp = (float*)Cout + (size_t)m * N + c;
#pragma unroll
                for (int r = 0; r < 4; ++r) cp[(size_t)r * N] = acc[mi][ni][r];
            } else if (MODE == 1) {
                u16* cp = (u16*)Cout + (size_t)m * N + c;
#pragma unroll
                for (int r = 0; r < 4; ++r) cp[(size_t)r * N] = f2bf(acc[mi][ni][r]);
            } else {
                const int hh = c >> 8, j = c & 255;
                const int bb = m >> 11, t = m & 2047;
                if (j < 128) {
#pragma unroll
                    for (int r = 0; r < 4; ++r)
                        kbuf[(((size_t)hh * 2 + bb) * 2048 + t + r) * 192 + j] =
                            f2bf(acc[mi][ni][r]);
                } else {
                    u16x4 pk;
#pragma unroll
                    for (int r = 0; r < 4; ++r) pk[r] = f2bf(acc[mi][ni][r]);
                    *(u16x4*)&vT[(((size_t)hh * 2 + bb) * 128 + (j - 128)) * 2048 + t] = pk;
                }
            }
        }
}

// NOTE: the reference computes q_pe = rotary(q_pe) but then uses the ORIGINAL
// (unrotated) q in the score einsum — the rotated q_pe is dead code there.
// So q gets NO RoPE; only k_pe is rotated.

// ---------------------------------------------------------------------------
// Per-token: rmsnorm(kv_c)*w -> kvn_bf; rotary(k_pe) -> kbuf[h][b][t][128..191].
// ---------------------------------------------------------------------------
__global__ __launch_bounds__(256) void kv_fix(const float* __restrict__ kv_raw,
                                              const float* __restrict__ w,
                                              const float* __restrict__ fcos,
                                              const float* __restrict__ fsin,
                                              u16* __restrict__ kvn_bf,
                                              u16* __restrict__ kbuf) {
    const int row = blockIdx.x;
    const int tid = threadIdx.x;
    const float* src = kv_raw + (size_t)row * 640;
    const float v0 = src[tid];
    const float v1 = src[256 + tid];
    float ss = v0 * v0 + v1 * v1;
#pragma unroll
    for (int off = 32; off > 0; off >>= 1) ss += __shfl_down(ss, off, 64);
    __shared__ float red[4];
    __shared__ float kpe_s[64];
    if ((tid & 63) == 0) red[tid >> 6] = ss;
    if (tid < 32) {
        const int s = row & (SEQ - 1);
        const float c  = fcos[s * 32 + tid];
        const float sn = fsin[s * 32 + tid];
        const float xr = src[KV_LORA + 2 * tid];
        const float xi = src[KV_LORA + 2 * tid + 1];
        kpe_s[2 * tid]     = xr * c - xi * sn;
        kpe_s[2 * tid + 1] = xr * sn + xi * c;
    }
    __syncthreads();
    const float tot = red[0] + red[1] + red[2] + red[3];
    const float inv = rsqrtf(tot * (1.0f / KV_LORA) + EPSF);
    kvn_bf[(size_t)row * KV_LORA + tid]       = f2bf(v0 * inv * w[tid]);
    kvn_bf[(size_t)row * KV_LORA + 256 + tid] = f2bf(v1 * inv * w[256 + tid]);
    const int bb = row >> 11, t = row & 2047;
    const int hh = tid >> 4, dg = (tid & 15) * 4;
    u16x4 pk;
#pragma unroll
    for (int j = 0; j < 4; ++j) pk[j] = f2bf(kpe_s[dg + j]);
    *(u16x4*)&kbuf[(((size_t)hh * 2 + bb) * 2048 + t) * 192 + 128 + dg] = pk;
}

// ---------------------------------------------------------------------------
// MFMA flash attention v5: pipelined staging.
//   - K tiles double-buffered in LDS; next tile's global_load_lds issued
//     BEFORE computing the current tile; ONE barrier per tile (no mid-loop
//     vmcnt(0) drain between stage and compute).
//   - V^T staging removed from LDS: fragments loaded straight to registers
//     (2x reuse only, L2-resident per (h,b)); s=0 half issued at iter top,
//     s=1 half after QK -> latency hides under QK+softmax.
//   - s_setprio(1) around MFMA clusters (T5).
// LDS: 2*24KB (K dbuf) + 18KB (Ps) = 66KB -> 2 blocks/CU (132KB < 160KB).
// Grid pairing unchanged: co-resident qt pairs sum to 15 for load balance.
// ---------------------------------------------------------------------------
__global__ __launch_bounds__(256, 2) void attn_mfma(const u16* __restrict__ qbf,
                                                    const u16* __restrict__ kbuf,
                                                    const u16* __restrict__ vT,
                                                    u16* __restrict__ att,
                                                    float scale) {
    __shared__ __attribute__((aligned(16))) u16 Ks[2][6 * 64 * 32];
    __shared__ __attribute__((aligned(16))) u16 Ps[4][32 * 72];
    const int x = blockIdx.x;
    const int qt_base = (x & 1) ? (15 - (x >> 1)) : (x >> 1);
    const int qt = blockIdx.z ? (15 - qt_base) : qt_base;
    const int h = blockIdx.y, b = blockIdx.z;
    const int tid = threadIdx.x, wave = tid >> 6, lane = tid & 63;
    const int l15 = lane & 15, lg = lane >> 4;

    const u16* kb_base = kbuf + ((size_t)(h * 2 + b)) * 2048 * 192;
    const u16* vt_base = vT   + ((size_t)(h * 2 + b)) * 128 * 2048;

    // Q B-frags for this wave's 2 q-groups
    int qrow[2];
    bf16x8 qf[2][6];
#pragma unroll
    for (int g = 0; g < 2; ++g) {
        qrow[g] = qt * 128 + g * 64 + wave * 16 + l15;
        const size_t qoff = ((size_t)(b * SEQ + qrow[g])) * QROW + h * 192 + lg * 8;
#pragma unroll
        for (int s = 0; s < 6; ++s) qf[g][s] = *(const bf16x8*)&qbf[qoff + s * 32];
    }

    floatx4 oacc[2][8];
#pragma unroll
    for (int g = 0; g < 2; ++g)
#pragma unroll
        for (int v = 0; v < 8; ++v) oacc[g][v] = 0.f;
    float m_run[2] = {-1e30f, -1e30f}, l_run[2] = {0.f, 0.f};

    // stage K tile [64][192] -> Ks[bufi][s][t][32]; 6 calls per wave
    auto stageK = [&](int bufi, int tt) {
#pragma unroll
        for (int i = 0; i < 6; ++i) {
            const int base = (wave * 6 + i) * 64;
            const int slot = base + lane;
            const int s = slot >> 8, r = slot & 255, tk = r >> 2, ch = r & 3;
            async_copy16(kb_base + ((size_t)(tt + tk)) * 192 + s * 32 + ch * 8,
                         &Ks[bufi][base * 8]);
        }
    };

    const int kt_max = 2 * qt + 1;
    stageK(0, 0);
    __syncthreads();

    for (int kt = 0; kt <= kt_max; ++kt) {
        const int t0 = kt * 64;
        const int cur = kt & 1;

        // V^T fragments direct from global (registers), s=0 half first.
        // vf layout matches old Vs read: V^T[vt*16+l15][t0 + s*32 + lg*8 ..+7]
        const u16* vrow = vt_base + (size_t)l15 * 2048 + t0 + lg * 8;
        bf16x8 vregA[8], vregB[8];
#pragma unroll
        for (int vt = 0; vt < 8; ++vt)
            vregA[vt] = *(const bf16x8*)&vrow[(size_t)vt * 16 * 2048];

        // issue next K tile stage BEFORE compute (overlap with this tile)
        if (kt < kt_max) stageK(cur ^ 1, t0 + 64);

        // S^T[64t][16q] per group: share each K frag across both q-groups
        floatx4 sacc[2][4];
#pragma unroll
        for (int g = 0; g < 2; ++g)
#pragma unroll
            for (int mt = 0; mt < 4; ++mt) sacc[g][mt] = 0.f;
        __builtin_amdgcn_s_setprio(1);
#pragma unroll
        for (int s = 0; s < 6; ++s) {
#pragma unroll
            for (int mt = 0; mt < 4; ++mt) {
                const bf16x8 kf = *(const bf16x8*)&Ks[cur][(s * 64 + mt * 16 + l15) * 32 + lg * 8];
#pragma unroll
                for (int g = 0; g < 2; ++g)
                    sacc[g][mt] = __builtin_amdgcn_mfma_f32_16x16x32_bf16(
                        kf, qf[g][s], sacc[g][mt], 0, 0, 0);
            }
        }
        __builtin_amdgcn_s_setprio(0);

        // V^T s=1 half (latency hides under softmax)
#pragma unroll
        for (int vt = 0; vt < 8; ++vt)
            vregB[vt] = *(const bf16x8*)&vrow[(size_t)vt * 16 * 2048 + 32];

        // online softmax per q-col
        float alpha[2];
#pragma unroll
        for (int g = 0; g < 2; ++g) {
            const bool full = (t0 + 63) <= (qt * 128 + g * 64 + wave * 16);
            float p[16];
            float tmax = -1e30f;
#pragma unroll
            for (int mt = 0; mt < 4; ++mt)
#pragma unroll
                for (int r = 0; r < 4; ++r) {
                    float v = sacc[g][mt][r] * scale;
                    if (!full) {
                        const int tglob = t0 + mt * 16 + lg * 4 + r;
                        v = (tglob <= qrow[g]) ? v : -1e30f;
                    }
                    p[mt * 4 + r] = v;
                    tmax = fmaxf(tmax, v);
                }
            tmax = fmaxf(tmax, __shfl_xor(tmax, 16));
            tmax = fmaxf(tmax, __shfl_xor(tmax, 32));
            const float mnew = fmaxf(m_run[g], tmax);
            alpha[g] = __expf(m_run[g] - mnew);
            m_run[g] = mnew;
            float rsum = 0.f;
#pragma unroll
            for (int k = 0; k < 16; ++k) { p[k] = __expf(p[k] - mnew); rsum += p[k]; }
            rsum += __shfl_xor(rsum, 16);
            rsum += __shfl_xor(rsum, 32);
            l_run[g] = l_run[g] * alpha[g] + rsum;
#pragma unroll
            for (int mt = 0; mt < 4; ++mt) {
                u16x4 pk;
#pragma unroll
                for (int r = 0; r < 4; ++r) pk[r] = f2bf(p[mt * 4 + r]);
                *(u16x4*)&Ps[wave][(g * 16 + l15) * 72 + mt * 16 + lg * 4] = pk;
            }
        }
        // rescale O by alpha per q-row
#pragma unroll
        for (int g = 0; g < 2; ++g) {
            float af[4];
#pragma unroll
            for (int r = 0; r < 4; ++r) af[r] = __shfl(alpha[g], lg * 4 + r);
#pragma unroll
            for (int vt = 0; vt < 8; ++vt)
#pragma unroll
                for (int r = 0; r < 4; ++r) oacc[g][vt][r] *= af[r];
        }
        // O[g][16q][128v] += P @ V
        __builtin_amdgcn_s_setprio(1);
#pragma unroll
        for (int s = 0; s < 2; ++s) {
            bf16x8 pf[2];
#pragma unroll
            for (int g = 0; g < 2; ++g)
                pf[g] = *(const bf16x8*)&Ps[wave][(g * 16 + l15) * 72 + s * 32 + lg * 8];
#pragma unroll
            for (int vt = 0; vt < 8; ++vt) {
                const bf16x8 vf = s ? vregB[vt] : vregA[vt];
#pragma unroll
                for (int g = 0; g < 2; ++g)
                    oacc[g][vt] = __builtin_amdgcn_mfma_f32_16x16x32_bf16(
                        pf[g], vf, oacc[g][vt], 0, 0, 0);
            }
        }
        __builtin_amdgcn_s_setprio(0);

        // single barrier per tile: (a) all waves done reading Ks[cur] before
        // next iter overwrites it, (b) vmcnt(0) drain makes Ks[cur^1] (tile
        // kt+1, issued at iter top) visible for next iter's compute.
        __syncthreads();
    }
    // epilogue: divide by l, store bf16
#pragma unroll
    for (int g = 0; g < 2; ++g) {
        float lf[4];
#pragma unroll
        for (int r = 0; r < 4; ++r) lf[r] = 1.0f / __shfl(l_run[g], lg * 4 + r);
#pragma unroll
        for (int vt = 0; vt < 8; ++vt)
#pragma unroll
            for (int r = 0; r < 4; ++r) {
                const int orow = b * SEQ + qt * 128 + g * 64 + wave * 16 + lg * 4 + r;
                att[(size_t)orow * 2048 + h * 128 + vt * 16 + l15] =
                    f2bf(oacc[g][vt][r] * lf[r]);
            }
    }
}

// ---------------------------------------------------------------------------
extern "C" void kernel_launch(void* const* d_in, const int* in_sizes, int n_in,
                              void* d_out, int out_size, void* d_ws, size_t ws_size,
                              hipStream_t stream) {
    const float* x     = (const float*)d_in[0];
    const float* wq    = (const float*)d_in[1];
    const float* wkv_a = (const float*)d_in[2];
    const float* knw   = (const float*)d_in[3];
    const float* wkv_b = (const float*)d_in[4];
    const float* wo    = (const float*)d_in[5];
    const float* fcos  = (const float*)d_in[6];
    const float* fsin  = (const float*)d_in[7];
    float* out = (float*)d_out;

    char* w = (char*)d_ws;
    u16*   x_bf    = (u16*)w;  w += (size_t)NTOK * 2048 * 2;
    u16*   wq_bf   = (u16*)w;  w += (size_t)QROW * 2048 * 2;
    u16*   wkva_bf = (u16*)w;  w += (size_t)640 * 2048 * 2;
    u16*   wkvb_bf = (u16*)w;  w += (size_t)KVBROW * KV_LORA * 2;
    u16*   wo_bf   = (u16*)w;  w += (size_t)2048 * 2048 * 2;
    u16*   q_bf    = (u16*)w;  w += (size_t)NTOK * QROW * 2;
    float* kv_raw  = (float*)w; w += (size_t)NTOK * 640 * 4;
    u16*   kvn_bf  = (u16*)w;  w += (size_t)NTOK * KV_LORA * 2;
    u16*   kbuf    = (u16*)w;  w += (size_t)NH * NB * SEQ * 192 * 2;
    u16*   vT      = (u16*)w;  w += (size_t)NH * NB * 128 * SEQ * 2;
    u16*   att_bf  = (u16*)w;  w += (size_t)NTOK * 2048 * 2;

    const double mm = 0.1 * 1.0 * log(40.0) + 1.0;
    const float scale = (float)((1.0 / sqrt((double)D_QK)) * mm * mm);

    dim3 blk(256);
    cast_all<<<dim3(21760), blk, 0, stream>>>(x, wq, wkv_a, wkv_b, wo,
                                              x_bf, wq_bf, wkva_bf, wkvb_bf, wo_bf);
    gemm_mfma<1><<<dim3(QROW / 128, NTOK / 128), blk, 0, stream>>>(
        x_bf, wq_bf, q_bf, nullptr, nullptr, NTOK, QROW, 2048);
    gemm_mfma<0><<<dim3(640 / 128, NTOK / 128), blk, 0, stream>>>(
        x_bf, wkva_bf, kv_raw, nullptr, nullptr, NTOK, 640, 2048);
    kv_fix<<<dim3(NTOK), blk, 0, stream>>>(kv_raw, knw, fcos, fsin, kvn_bf, kbuf);
    gemm_mfma<2><<<dim3(KVBROW / 128, NTOK / 128), blk, 0, stream>>>(
        kvn_bf, wkvb_bf, nullptr, kbuf, vT, NTOK, KVBROW, KV_LORA);
    attn_mfma<<<dim3(SEQ / 128, NH, NB), blk, 0, stream>>>(q_bf, kbuf, vT, att_bf, scale);
    gemm_mfma<0><<<dim3(2048 / 128, NTOK / 128), blk, 0, stream>>>(
        att_bf, wo_bf, out, nullptr, nullptr, NTOK, 2048, 2048);
}

// Round 3
// 441.147 us; speedup vs baseline: 1.1670x; 1.1670x over previous
//
#include <hip/hip_runtime.h>
#include <math.h>

#define NH      16
#define D_NOPE  128
#define D_ROPE  64
#define D_QK    192
#define D_V     128
#define KV_LORA 512
#define NB      2
#define SEQ     2048
#define NTOK    (NB*SEQ)          // 4096
#define QROW    (NH*D_QK)         // 3072
#define KVBROW  (NH*(D_NOPE+D_V)) // 4096
#define EPSF    1e-6f

typedef unsigned short u16;
typedef float  floatx4 __attribute__((ext_vector_type(4)));
typedef __bf16 bf16x8  __attribute__((ext_vector_type(8)));
typedef u16    u16x4   __attribute__((ext_vector_type(4)));
typedef u16    u16x8   __attribute__((ext_vector_type(8)));

__device__ __forceinline__ u16 f2bf(float f) {
    unsigned u = __builtin_bit_cast(unsigned, f);
    return (u16)((u + 0x7fffu + ((u >> 16) & 1u)) >> 16);
}

__device__ __forceinline__ void async_copy16(const void* g, void* l) {
    __builtin_amdgcn_global_load_lds(
        (const __attribute__((address_space(1))) unsigned int*)g,
        (__attribute__((address_space(3))) unsigned int*)l,
        16, 0, 0);
}

// ---------------------------------------------------------------------------
// Fused fp32->bf16 cast of all 5 weight/activation arrays in ONE dispatch.
// ---------------------------------------------------------------------------
__global__ __launch_bounds__(256) void cast_all(const float* __restrict__ x,
                                                const float* __restrict__ wq,
                                                const float* __restrict__ wkva,
                                                const float* __restrict__ wkvb,
                                                const float* __restrict__ wo,
                                                u16* __restrict__ xb,
                                                u16* __restrict__ wqb,
                                                u16* __restrict__ wkvab,
                                                u16* __restrict__ wkvbb,
                                                u16* __restrict__ wob) {
    int blk = blockIdx.x;
    const float* src; u16* dst; bool pad = false;
    if (blk < 8192)        { src = x;    dst = xb; }
    else if (blk < 14336)  { blk -= 8192;  src = wq;   dst = wqb; }
    else if (blk < 15616)  { blk -= 14336; src = wkva; dst = wkvab; pad = true; }
    else if (blk < 17664)  { blk -= 15616; src = wkvb; dst = wkvbb; }
    else                   { blk -= 17664; src = wo;   dst = wob; }
    const int i = (blk * 256 + threadIdx.x) * 4;
    u16x4 o;
    if (pad && (i >> 11) >= 576) {
        o[0] = 0; o[1] = 0; o[2] = 0; o[3] = 0;
    } else {
        const float4 v = *(const float4*)&src[i];
        o[0] = f2bf(v.x); o[1] = f2bf(v.y); o[2] = f2bf(v.z); o[3] = f2bf(v.w);
    }
    *(u16x4*)&dst[i] = o;
}

// ---------------------------------------------------------------------------
// bf16 NT MFMA GEMM (m97 recipe), templated epilogue:
//   MODE 0: fp32 C[M,N] | MODE 1: bf16 C[M,N] | MODE 2: kv-split kbuf/vT.
// ---------------------------------------------------------------------------
template<int MODE>
__global__ __launch_bounds__(256) void gemm_mfma(const u16* __restrict__ A,
                                                 const u16* __restrict__ B,
                                                 void* __restrict__ Cout,
                                                 u16* __restrict__ kbuf,
                                                 u16* __restrict__ vT,
                                                 int M, int N, int K) {
    __shared__ u16 As[128 * 32];
    __shared__ u16 Bs[128 * 32];
    const int tid  = threadIdx.x;
    const int wave = tid >> 6, lane = tid & 63;
    const int m0 = blockIdx.y * 128, n0 = blockIdx.x * 128;
    const int wm = (wave & 1) * 64, wn = (wave >> 1) * 64;

    const int srow = wave * 32 + (lane >> 2);
    const int kch  = (lane & 3) * 8;
    const u16* gA0 = A + (size_t)(m0 + srow) * K + kch;
    const u16* gA1 = gA0 + (size_t)16 * K;
    const u16* gB0 = B + (size_t)(n0 + srow) * K + kch;
    const u16* gB1 = gB0 + (size_t)16 * K;
    u16* lA0 = &As[(wave * 32) * 32];
    u16* lA1 = &As[(wave * 32 + 16) * 32];
    u16* lB0 = &Bs[(wave * 32) * 32];
    u16* lB1 = &Bs[(wave * 32 + 16) * 32];

    floatx4 acc[4][4];
#pragma unroll
    for (int i = 0; i < 4; ++i)
#pragma unroll
        for (int j = 0; j < 4; ++j) acc[i][j] = 0.f;

    const int lrow = lane & 15;
    const int lkh  = (lane >> 4) * 8;

    for (int k0 = 0; k0 < K; k0 += 32) {
        __syncthreads();
        async_copy16(gA0 + k0, lA0);
        async_copy16(gA1 + k0, lA1);
        async_copy16(gB0 + k0, lB0);
        async_copy16(gB1 + k0, lB1);
        __syncthreads();
        bf16x8 a[4], b[4];
#pragma unroll
        for (int mi = 0; mi < 4; ++mi)
            a[mi] = *(const bf16x8*)&As[(wm + mi * 16 + lrow) * 32 + lkh];
#pragma unroll
        for (int ni = 0; ni < 4; ++ni)
            b[ni] = *(const bf16x8*)&Bs[(wn + ni * 16 + lrow) * 32 + lkh];
#pragma unroll
        for (int mi = 0; mi < 4; ++mi)
#pragma unroll
            for (int ni = 0; ni < 4; ++ni)
                acc[mi][ni] = __builtin_amdgcn_mfma_f32_16x16x32_bf16(
                    a[mi], b[ni], acc[mi][ni], 0, 0, 0);
    }

    const int crow = (lane >> 4) * 4, ccol = lane & 15;
#pragma unroll
    for (int mi = 0; mi < 4; ++mi)
#pragma unroll
        for (int ni = 0; ni < 4; ++ni) {
            const int m = m0 + wm + mi * 16 + crow;
            const int c = n0 + wn + ni * 16 + ccol;
            if (MODE == 0) {
                float* cp = (float*)Cout + (size_t)m * N + c;
#pragma unroll
                for (int r = 0; r < 4; ++r) cp[(size_t)r * N] = acc[mi][ni][r];
            } else if (MODE == 1) {
                u16* cp = (u16*)Cout + (size_t)m * N + c;
#pragma unroll
                for (int r = 0; r < 4; ++r) cp[(size_t)r * N] = f2bf(acc[mi][ni][r]);
            } else {
                const int hh = c >> 8, j = c & 255;
                const int bb = m >> 11, t = m & 2047;
                if (j < 128) {
#pragma unroll
                    for (int r = 0; r < 4; ++r)
                        kbuf[(((size_t)hh * 2 + bb) * 2048 + t + r) * 192 + j] =
                            f2bf(acc[mi][ni][r]);
                } else {
                    u16x4 pk;
#pragma unroll
                    for (int r = 0; r < 4; ++r) pk[r] = f2bf(acc[mi][ni][r]);
                    *(u16x4*)&vT[(((size_t)hh * 2 + bb) * 128 + (j - 128)) * 2048 + t] = pk;
                }
            }
        }
}

// NOTE: the reference computes q_pe = rotary(q_pe) but then uses the ORIGINAL
// (unrotated) q in the score einsum — the rotated q_pe is dead code there.
// So q gets NO RoPE; only k_pe is rotated.

// ---------------------------------------------------------------------------
// Per-token: rmsnorm(kv_c)*w -> kvn_bf; rotary(k_pe) -> kbuf[h][b][t][128..191].
// ---------------------------------------------------------------------------
__global__ __launch_bounds__(256) void kv_fix(const float* __restrict__ kv_raw,
                                              const float* __restrict__ w,
                                              const float* __restrict__ fcos,
                                              const float* __restrict__ fsin,
                                              u16* __restrict__ kvn_bf,
                                              u16* __restrict__ kbuf) {
    const int row = blockIdx.x;
    const int tid = threadIdx.x;
    const float* src = kv_raw + (size_t)row * 640;
    const float v0 = src[tid];
    const float v1 = src[256 + tid];
    float ss = v0 * v0 + v1 * v1;
#pragma unroll
    for (int off = 32; off > 0; off >>= 1) ss += __shfl_down(ss, off, 64);
    __shared__ float red[4];
    __shared__ float kpe_s[64];
    if ((tid & 63) == 0) red[tid >> 6] = ss;
    if (tid < 32) {
        const int s = row & (SEQ - 1);
        const float c  = fcos[s * 32 + tid];
        const float sn = fsin[s * 32 + tid];
        const float xr = src[KV_LORA + 2 * tid];
        const float xi = src[KV_LORA + 2 * tid + 1];
        kpe_s[2 * tid]     = xr * c - xi * sn;
        kpe_s[2 * tid + 1] = xr * sn + xi * c;
    }
    __syncthreads();
    const float tot = red[0] + red[1] + red[2] + red[3];
    const float inv = rsqrtf(tot * (1.0f / KV_LORA) + EPSF);
    kvn_bf[(size_t)row * KV_LORA + tid]       = f2bf(v0 * inv * w[tid]);
    kvn_bf[(size_t)row * KV_LORA + 256 + tid] = f2bf(v1 * inv * w[256 + tid]);
    const int bb = row >> 11, t = row & 2047;
    const int hh = tid >> 4, dg = (tid & 15) * 4;
    u16x4 pk;
#pragma unroll
    for (int j = 0; j < 4; ++j) pk[j] = f2bf(kpe_s[dg + j]);
    *(u16x4*)&kbuf[(((size_t)hh * 2 + bb) * 2048 + t) * 192 + 128 + dg] = pk;
}

// ---------------------------------------------------------------------------
// MFMA flash attention v6: v4 structure + pipelined LDS staging.
//   - Ks double-buffered [2][24KB]; K(kt+1) issued at iteration TOP, before
//     QK compute -> at barrier B it has had ~QK+softmax time to land.
//   - Vs single-buffered in LDS (16KB, shared by all 4 waves — the v5
//     per-wave global gather is reverted); V(kt) also issued at iter top,
//     first consumed only after barrier B.
//   - Two barriers/iter like v4, but neither drains a COLD 40KB transfer:
//     B drains loads issued ~700cy earlier; C has vmcnt already 0 (cheap).
//   - Ps shrunk 18KB -> 9KB via per-g reuse (per-wave buffer, no barrier
//     interaction); PV restructured g-outer (vf re-read for g=1).
//   - T13 defer-max (THR=8): skip O-rescale when tile max doesn't grow.
// LDS: 48 + 16 + 9 = 73KB -> 2 blocks/CU (146KB < 160KB).
// ---------------------------------------------------------------------------
__global__ __launch_bounds__(256, 2) void attn_mfma(const u16* __restrict__ qbf,
                                                    const u16* __restrict__ kbuf,
                                                    const u16* __restrict__ vT,
                                                    u16* __restrict__ att,
                                                    float scale) {
    __shared__ __attribute__((aligned(16))) u16 Ks[2][6 * 64 * 32];
    __shared__ __attribute__((aligned(16))) u16 Vs[2 * 128 * 32];
    __shared__ __attribute__((aligned(16))) u16 Ps[4][16 * 72];
    const int x = blockIdx.x;
    const int qt_base = (x & 1) ? (15 - (x >> 1)) : (x >> 1);
    const int qt = blockIdx.z ? (15 - qt_base) : qt_base;
    const int h = blockIdx.y, b = blockIdx.z;
    const int tid = threadIdx.x, wave = tid >> 6, lane = tid & 63;
    const int l15 = lane & 15, lg = lane >> 4;

    const u16* kb_base = kbuf + ((size_t)(h * 2 + b)) * 2048 * 192;
    const u16* vt_base = vT   + ((size_t)(h * 2 + b)) * 128 * 2048;

    // Q B-frags for this wave's 2 q-groups
    int qrow[2];
    bf16x8 qf[2][6];
#pragma unroll
    for (int g = 0; g < 2; ++g) {
        qrow[g] = qt * 128 + g * 64 + wave * 16 + l15;
        const size_t qoff = ((size_t)(b * SEQ + qrow[g])) * QROW + h * 192 + lg * 8;
#pragma unroll
        for (int s = 0; s < 6; ++s) qf[g][s] = *(const bf16x8*)&qbf[qoff + s * 32];
    }

    floatx4 oacc[2][8];
#pragma unroll
    for (int g = 0; g < 2; ++g)
#pragma unroll
        for (int v = 0; v < 8; ++v) oacc[g][v] = 0.f;
    float m_run[2] = {-1e30f, -1e30f}, l_run[2] = {0.f, 0.f};

    // stage K tile [64][192] -> Ks[bufi][s][t][32]; 6 calls per wave
    auto stageK = [&](int bufi, int tt) {
#pragma unroll
        for (int i = 0; i < 6; ++i) {
            const int base = (wave * 6 + i) * 64;
            const int slot = base + lane;
            const int s = slot >> 8, r = slot & 255, tk = r >> 2, ch = r & 3;
            async_copy16(kb_base + ((size_t)(tt + tk)) * 192 + s * 32 + ch * 8,
                         &Ks[bufi][base * 8]);
        }
    };
    // stage V^T tile [128][64] -> Vs[s][v][32]; 4 calls per wave
    auto stageV = [&](int tt) {
#pragma unroll
        for (int i = 0; i < 4; ++i) {
            const int base = (wave * 4 + i) * 64;
            const int slot = base + lane;
            const int s = slot >> 9, r = slot & 511, v = r >> 2, ch = r & 3;
            async_copy16(vt_base + ((size_t)v) * 2048 + tt + s * 32 + ch * 8,
                         &Vs[base * 8]);
        }
    };

    const int kt_max = 2 * qt + 1;
    stageK(0, 0);
    __syncthreads();                 // prologue: K(0) ready

    for (int kt = 0; kt <= kt_max; ++kt) {
        const int t0 = kt * 64;
        const int cur = kt & 1;

        // issue this tile's V and next tile's K BEFORE compute (overlap)
        stageV(t0);
        if (kt < kt_max) stageK(cur ^ 1, t0 + 64);

        // S^T[64t][16q] per group: share each K frag across both q-groups
        floatx4 sacc[2][4];
#pragma unroll
        for (int g = 0; g < 2; ++g)
#pragma unroll
            for (int mt = 0; mt < 4; ++mt) sacc[g][mt] = 0.f;
        __builtin_amdgcn_s_setprio(1);
#pragma unroll
        for (int s = 0; s < 6; ++s) {
#pragma unroll
            for (int mt = 0; mt < 4; ++mt) {
                const bf16x8 kf = *(const bf16x8*)&Ks[cur][(s * 64 + mt * 16 + l15) * 32 + lg * 8];
#pragma unroll
                for (int g = 0; g < 2; ++g)
                    sacc[g][mt] = __builtin_amdgcn_mfma_f32_16x16x32_bf16(
                        kf, qf[g][s], sacc[g][mt], 0, 0, 0);
            }
        }
        __builtin_amdgcn_s_setprio(0);

        // online softmax per q-col; pack P to bf16 regs (pk) for post-barrier PV
        u16x4 pk[2][4];
#pragma unroll
        for (int g = 0; g < 2; ++g) {
            const bool full = (t0 + 63) <= (qt * 128 + g * 64 + wave * 16);
            float p[16];
            float tmax = -1e30f;
#pragma unroll
            for (int mt = 0; mt < 4; ++mt)
#pragma unroll
                for (int r = 0; r < 4; ++r) {
                    float v = sacc[g][mt][r] * scale;
                    if (!full) {
                        const int tglob = t0 + mt * 16 + lg * 4 + r;
                        v = (tglob <= qrow[g]) ? v : -1e30f;
                    }
                    p[mt * 4 + r] = v;
                    tmax = fmaxf(tmax, v);
                }
            tmax = fmaxf(tmax, __shfl_xor(tmax, 16));
            tmax = fmaxf(tmax, __shfl_xor(tmax, 32));
            // T13 defer-max: if tile max grew by <= 8, keep old m (p <= e^8,
            // safe in bf16/f32) and skip the O-rescale pass entirely.
            const bool defer = __all(tmax <= m_run[g] + 8.0f);
            float alph = 1.0f;
            float mnew = m_run[g];
            if (!defer) {
                mnew = fmaxf(m_run[g], tmax);
                alph = __expf(m_run[g] - mnew);
                m_run[g] = mnew;
            }
            float rsum = 0.f;
#pragma unroll
            for (int k = 0; k < 16; ++k) { p[k] = __expf(p[k] - mnew); rsum += p[k]; }
            rsum += __shfl_xor(rsum, 16);
            rsum += __shfl_xor(rsum, 32);
            if (!defer) {
                l_run[g] = l_run[g] * alph + rsum;
                float af[4];
#pragma unroll
                for (int r = 0; r < 4; ++r) af[r] = __shfl(alph, lg * 4 + r);
#pragma unroll
                for (int vt = 0; vt < 8; ++vt)
#pragma unroll
                    for (int r = 0; r < 4; ++r) oacc[g][vt][r] *= af[r];
            } else {
                l_run[g] += rsum;
            }
#pragma unroll
            for (int mt = 0; mt < 4; ++mt)
#pragma unroll
                for (int r = 0; r < 4; ++r) pk[g][mt][r] = f2bf(p[mt * 4 + r]);
        }

        // barrier B: makes Vs(kt) + Ks[cur^1](kt+1) visible; both were issued
        // at iter top, so the vmcnt(0) drain here is mostly already satisfied.
        __syncthreads();

        // O[g][16q][128v] += P @ V, g-outer with per-g Ps reuse (per-wave
        // buffer; within-wave write->read ordering via lgkmcnt, no barrier).
        __builtin_amdgcn_s_setprio(1);
#pragma unroll
        for (int g = 0; g < 2; ++g) {
#pragma unroll
            for (int mt = 0; mt < 4; ++mt)
                *(u16x4*)&Ps[wave][l15 * 72 + mt * 16 + lg * 4] = pk[g][mt];
            bf16x8 pf[2];
#pragma unroll
            for (int s = 0; s < 2; ++s)
                pf[s] = *(const bf16x8*)&Ps[wave][l15 * 72 + s * 32 + lg * 8];
#pragma unroll
            for (int s = 0; s < 2; ++s)
#pragma unroll
                for (int vt = 0; vt < 8; ++vt) {
                    const bf16x8 vf = *(const bf16x8*)&Vs[(s * 128 + vt * 16 + l15) * 32 + lg * 8];
                    oacc[g][vt] = __builtin_amdgcn_mfma_f32_16x16x32_bf16(
                        pf[s], vf, oacc[g][vt], 0, 0, 0);
                }
        }
        __builtin_amdgcn_s_setprio(0);

        // barrier C: all waves done reading Vs + Ks[cur] before next iter's
        // stage overwrites them. No VMEM issued since B -> cheap barrier.
        __syncthreads();
    }
    // epilogue: divide by l, store bf16
#pragma unroll
    for (int g = 0; g < 2; ++g) {
        float lf[4];
#pragma unroll
        for (int r = 0; r < 4; ++r) lf[r] = 1.0f / __shfl(l_run[g], lg * 4 + r);
#pragma unroll
        for (int vt = 0; vt < 8; ++vt)
#pragma unroll
            for (int r = 0; r < 4; ++r) {
                const int orow = b * SEQ + qt * 128 + g * 64 + wave * 16 + lg * 4 + r;
                att[(size_t)orow * 2048 + h * 128 + vt * 16 + l15] =
                    f2bf(oacc[g][vt][r] * lf[r]);
            }
    }
}

// ---------------------------------------------------------------------------
extern "C" void kernel_launch(void* const* d_in, const int* in_sizes, int n_in,
                              void* d_out, int out_size, void* d_ws, size_t ws_size,
                              hipStream_t stream) {
    const float* x     = (const float*)d_in[0];
    const float* wq    = (const float*)d_in[1];
    const float* wkv_a = (const float*)d_in[2];
    const float* knw   = (const float*)d_in[3];
    const float* wkv_b = (const float*)d_in[4];
    const float* wo    = (const float*)d_in[5];
    const float* fcos  = (const float*)d_in[6];
    const float* fsin  = (const float*)d_in[7];
    float* out = (float*)d_out;

    char* w = (char*)d_ws;
    u16*   x_bf    = (u16*)w;  w += (size_t)NTOK * 2048 * 2;
    u16*   wq_bf   = (u16*)w;  w += (size_t)QROW * 2048 * 2;
    u16*   wkva_bf = (u16*)w;  w += (size_t)640 * 2048 * 2;
    u16*   wkvb_bf = (u16*)w;  w += (size_t)KVBROW * KV_LORA * 2;
    u16*   wo_bf   = (u16*)w;  w += (size_t)2048 * 2048 * 2;
    u16*   q_bf    = (u16*)w;  w += (size_t)NTOK * QROW * 2;
    float* kv_raw  = (float*)w; w += (size_t)NTOK * 640 * 4;
    u16*   kvn_bf  = (u16*)w;  w += (size_t)NTOK * KV_LORA * 2;
    u16*   kbuf    = (u16*)w;  w += (size_t)NH * NB * SEQ * 192 * 2;
    u16*   vT      = (u16*)w;  w += (size_t)NH * NB * 128 * SEQ * 2;
    u16*   att_bf  = (u16*)w;  w += (size_t)NTOK * 2048 * 2;

    const double mm = 0.1 * 1.0 * log(40.0) + 1.0;
    const float scale = (float)((1.0 / sqrt((double)D_QK)) * mm * mm);

    dim3 blk(256);
    cast_all<<<dim3(21760), blk, 0, stream>>>(x, wq, wkv_a, wkv_b, wo,
                                              x_bf, wq_bf, wkva_bf, wkvb_bf, wo_bf);
    gemm_mfma<1><<<dim3(QROW / 128, NTOK / 128), blk, 0, stream>>>(
        x_bf, wq_bf, q_bf, nullptr, nullptr, NTOK, QROW, 2048);
    gemm_mfma<0><<<dim3(640 / 128, NTOK / 128), blk, 0, stream>>>(
        x_bf, wkva_bf, kv_raw, nullptr, nullptr, NTOK, 640, 2048);
    kv_fix<<<dim3(NTOK), blk, 0, stream>>>(kv_raw, knw, fcos, fsin, kvn_bf, kbuf);
    gemm_mfma<2><<<dim3(KVBROW / 128, NTOK / 128), blk, 0, stream>>>(
        kvn_bf, wkvb_bf, nullptr, kbuf, vT, NTOK, KVBROW, KV_LORA);
    attn_mfma<<<dim3(SEQ / 128, NH, NB), blk, 0, stream>>>(q_bf, kbuf, vT, att_bf, scale);
    gemm_mfma<0><<<dim3(2048 / 128, NTOK / 128), blk, 0, stream>>>(
        att_bf, wo_bf, out, nullptr, nullptr, NTOK, 2048, 2048);
}

// Round 4
// 432.394 us; speedup vs baseline: 1.1906x; 1.0202x over previous
//
#include <hip/hip_runtime.h>
#include <math.h>

#define NH      16
#define D_NOPE  128
#define D_ROPE  64
#define D_QK    192
#define D_V     128
#define KV_LORA 512
#define NB      2
#define SEQ     2048
#define NTOK    (NB*SEQ)          // 4096
#define QROW    (NH*D_QK)         // 3072
#define KVBROW  (NH*(D_NOPE+D_V)) // 4096
#define EPSF    1e-6f

typedef unsigned short u16;
typedef float  floatx4 __attribute__((ext_vector_type(4)));
typedef __bf16 bf16x8  __attribute__((ext_vector_type(8)));
typedef u16    u16x4   __attribute__((ext_vector_type(4)));
typedef u16    u16x8   __attribute__((ext_vector_type(8)));

__device__ __forceinline__ u16 f2bf(float f) {
    unsigned u = __builtin_bit_cast(unsigned, f);
    return (u16)((u + 0x7fffu + ((u >> 16) & 1u)) >> 16);
}

__device__ __forceinline__ void async_copy16(const void* g, void* l) {
    __builtin_amdgcn_global_load_lds(
        (const __attribute__((address_space(1))) unsigned int*)g,
        (__attribute__((address_space(3))) unsigned int*)l,
        16, 0, 0);
}

// ---------------------------------------------------------------------------
// Fused fp32->bf16 cast of all 5 weight/activation arrays in ONE dispatch.
// ---------------------------------------------------------------------------
__global__ __launch_bounds__(256) void cast_all(const float* __restrict__ x,
                                                const float* __restrict__ wq,
                                                const float* __restrict__ wkva,
                                                const float* __restrict__ wkvb,
                                                const float* __restrict__ wo,
                                                u16* __restrict__ xb,
                                                u16* __restrict__ wqb,
                                                u16* __restrict__ wkvab,
                                                u16* __restrict__ wkvbb,
                                                u16* __restrict__ wob) {
    int blk = blockIdx.x;
    const float* src; u16* dst; bool pad = false;
    if (blk < 8192)        { src = x;    dst = xb; }
    else if (blk < 14336)  { blk -= 8192;  src = wq;   dst = wqb; }
    else if (blk < 15616)  { blk -= 14336; src = wkva; dst = wkvab; pad = true; }
    else if (blk < 17664)  { blk -= 15616; src = wkvb; dst = wkvbb; }
    else                   { blk -= 17664; src = wo;   dst = wob; }
    const int i = (blk * 256 + threadIdx.x) * 4;
    u16x4 o;
    if (pad && (i >> 11) >= 576) {
        o[0] = 0; o[1] = 0; o[2] = 0; o[3] = 0;
    } else {
        const float4 v = *(const float4*)&src[i];
        o[0] = f2bf(v.x); o[1] = f2bf(v.y); o[2] = f2bf(v.z); o[3] = f2bf(v.w);
    }
    *(u16x4*)&dst[i] = o;
}

// ---------------------------------------------------------------------------
// bf16 NT MFMA GEMM (m97 recipe), templated epilogue:
//   MODE 0: fp32 C[M,N] | MODE 1: bf16 C[M,N] | MODE 2: kv-split kbuf/vT.
// ---------------------------------------------------------------------------
template<int MODE>
__global__ __launch_bounds__(256) void gemm_mfma(const u16* __restrict__ A,
                                                 const u16* __restrict__ B,
                                                 void* __restrict__ Cout,
                                                 u16* __restrict__ kbuf,
                                                 u16* __restrict__ vT,
                                                 int M, int N, int K) {
    __shared__ u16 As[128 * 32];
    __shared__ u16 Bs[128 * 32];
    const int tid  = threadIdx.x;
    const int wave = tid >> 6, lane = tid & 63;
    const int m0 = blockIdx.y * 128, n0 = blockIdx.x * 128;
    const int wm = (wave & 1) * 64, wn = (wave >> 1) * 64;

    const int srow = wave * 32 + (lane >> 2);
    const int kch  = (lane & 3) * 8;
    const u16* gA0 = A + (size_t)(m0 + srow) * K + kch;
    const u16* gA1 = gA0 + (size_t)16 * K;
    const u16* gB0 = B + (size_t)(n0 + srow) * K + kch;
    const u16* gB1 = gB0 + (size_t)16 * K;
    u16* lA0 = &As[(wave * 32) * 32];
    u16* lA1 = &As[(wave * 32 + 16) * 32];
    u16* lB0 = &Bs[(wave * 32) * 32];
    u16* lB1 = &Bs[(wave * 32 + 16) * 32];

    floatx4 acc[4][4];
#pragma unroll
    for (int i = 0; i < 4; ++i)
#pragma unroll
        for (int j = 0; j < 4; ++j) acc[i][j] = 0.f;

    const int lrow = lane & 15;
    const int lkh  = (lane >> 4) * 8;

    for (int k0 = 0; k0 < K; k0 += 32) {
        __syncthreads();
        async_copy16(gA0 + k0, lA0);
        async_copy16(gA1 + k0, lA1);
        async_copy16(gB0 + k0, lB0);
        async_copy16(gB1 + k0, lB1);
        __syncthreads();
        bf16x8 a[4], b[4];
#pragma unroll
        for (int mi = 0; mi < 4; ++mi)
            a[mi] = *(const bf16x8*)&As[(wm + mi * 16 + lrow) * 32 + lkh];
#pragma unroll
        for (int ni = 0; ni < 4; ++ni)
            b[ni] = *(const bf16x8*)&Bs[(wn + ni * 16 + lrow) * 32 + lkh];
#pragma unroll
        for (int mi = 0; mi < 4; ++mi)
#pragma unroll
            for (int ni = 0; ni < 4; ++ni)
                acc[mi][ni] = __builtin_amdgcn_mfma_f32_16x16x32_bf16(
                    a[mi], b[ni], acc[mi][ni], 0, 0, 0);
    }

    const int crow = (lane >> 4) * 4, ccol = lane & 15;
#pragma unroll
    for (int mi = 0; mi < 4; ++mi)
#pragma unroll
        for (int ni = 0; ni < 4; ++ni) {
            const int m = m0 + wm + mi * 16 + crow;
            const int c = n0 + wn + ni * 16 + ccol;
            if (MODE == 0) {
                float* cp = (float*)Cout + (size_t)m * N + c;
#pragma unroll
                for (int r = 0; r < 4; ++r) cp[(size_t)r * N] = acc[mi][ni][r];
            } else if (MODE == 1) {
                u16* cp = (u16*)Cout + (size_t)m * N + c;
#pragma unroll
                for (int r = 0; r < 4; ++r) cp[(size_t)r * N] = f2bf(acc[mi][ni][r]);
            } else {
                const int hh = c >> 8, j = c & 255;
                const int bb = m >> 11, t = m & 2047;
                if (j < 128) {
#pragma unroll
                    for (int r = 0; r < 4; ++r)
                        kbuf[(((size_t)hh * 2 + bb) * 2048 + t + r) * 192 + j] =
                            f2bf(acc[mi][ni][r]);
                } else {
                    u16x4 pk;
#pragma unroll
                    for (int r = 0; r < 4; ++r) pk[r] = f2bf(acc[mi][ni][r]);
                    *(u16x4*)&vT[(((size_t)hh * 2 + bb) * 128 + (j - 128)) * 2048 + t] = pk;
                }
            }
        }
}

// NOTE: the reference computes q_pe = rotary(q_pe) but then uses the ORIGINAL
// (unrotated) q in the score einsum — the rotated q_pe is dead code there.
// So q gets NO RoPE; only k_pe is rotated.

// ---------------------------------------------------------------------------
// Per-token: rmsnorm(kv_c)*w -> kvn_bf; rotary(k_pe) -> kbuf[h][b][t][128..191].
// ---------------------------------------------------------------------------
__global__ __launch_bounds__(256) void kv_fix(const float* __restrict__ kv_raw,
                                              const float* __restrict__ w,
                                              const float* __restrict__ fcos,
                                              const float* __restrict__ fsin,
                                              u16* __restrict__ kvn_bf,
                                              u16* __restrict__ kbuf) {
    const int row = blockIdx.x;
    const int tid = threadIdx.x;
    const float* src = kv_raw + (size_t)row * 640;
    const float v0 = src[tid];
    const float v1 = src[256 + tid];
    float ss = v0 * v0 + v1 * v1;
#pragma unroll
    for (int off = 32; off > 0; off >>= 1) ss += __shfl_down(ss, off, 64);
    __shared__ float red[4];
    __shared__ float kpe_s[64];
    if ((tid & 63) == 0) red[tid >> 6] = ss;
    if (tid < 32) {
        const int s = row & (SEQ - 1);
        const float c  = fcos[s * 32 + tid];
        const float sn = fsin[s * 32 + tid];
        const float xr = src[KV_LORA + 2 * tid];
        const float xi = src[KV_LORA + 2 * tid + 1];
        kpe_s[2 * tid]     = xr * c - xi * sn;
        kpe_s[2 * tid + 1] = xr * sn + xi * c;
    }
    __syncthreads();
    const float tot = red[0] + red[1] + red[2] + red[3];
    const float inv = rsqrtf(tot * (1.0f / KV_LORA) + EPSF);
    kvn_bf[(size_t)row * KV_LORA + tid]       = f2bf(v0 * inv * w[tid]);
    kvn_bf[(size_t)row * KV_LORA + 256 + tid] = f2bf(v1 * inv * w[256 + tid]);
    const int bb = row >> 11, t = row & 2047;
    const int hh = tid >> 4, dg = (tid & 15) * 4;
    u16x4 pk;
#pragma unroll
    for (int j = 0; j < 4; ++j) pk[j] = f2bf(kpe_s[dg + j]);
    *(u16x4*)&kbuf[(((size_t)hh * 2 + bb) * 2048 + t) * 192 + 128 + dg] = pk;
}

// ---------------------------------------------------------------------------
// MFMA flash attention v7: LDS-pipe attack.
//   - T2 XOR swizzle on Ks AND Vs (both-sides: linear DMA dest, inverse-
//     swizzled GLOBAL source ch^=(row>>1)&3, swizzled READ lg^=(l15>>1)&3).
//     Before: bank-quad = 4*(l15&1)+lg -> 4-aliased per 8-lane group (7.2M
//     conflict cycles). After: lanes 0..7 cover all 8 quads -> conflict-free.
//   - PV vf-hoist: pf[2][2] pulled to regs once; V read 16x/wave-iter (v6
//     g-outer read it 32x — hidden regression).
//   - T3/T4 counted vmcnt + raw s_barrier (m201/m218 pattern):
//       top:  stageV(kt), stageK(kt+1); vmcnt(10) [drain prev K, keep V4+K6];
//             barrier  -> Ks[cur] ready
//       QK + softmax + Ps->pf
//       vmcnt(6) [drain V only]; barrier -> Vs ready
//       PV
//       barrier [frees Vs+Ks[cur] for next iter's DMA]
//     Loads never drain to 0 in the main loop.
// LDS: 48 + 16 + 9 = 73KB -> 2 blocks/CU.
// ---------------------------------------------------------------------------
__global__ __launch_bounds__(256, 2) void attn_mfma(const u16* __restrict__ qbf,
                                                    const u16* __restrict__ kbuf,
                                                    const u16* __restrict__ vT,
                                                    u16* __restrict__ att,
                                                    float scale) {
    __shared__ __attribute__((aligned(16))) u16 Ks[2][6 * 64 * 32];
    __shared__ __attribute__((aligned(16))) u16 Vs[2 * 128 * 32];
    __shared__ __attribute__((aligned(16))) u16 Ps[4][16 * 72];
    const int x = blockIdx.x;
    const int qt_base = (x & 1) ? (15 - (x >> 1)) : (x >> 1);
    const int qt = blockIdx.z ? (15 - qt_base) : qt_base;
    const int h = blockIdx.y, b = blockIdx.z;
    const int tid = threadIdx.x, wave = tid >> 6, lane = tid & 63;
    const int l15 = lane & 15, lg = lane >> 4;
    const int lgs = lg ^ ((l15 >> 1) & 3);   // swizzled slot for Ks/Vs reads

    const u16* kb_base = kbuf + ((size_t)(h * 2 + b)) * 2048 * 192;
    const u16* vt_base = vT   + ((size_t)(h * 2 + b)) * 128 * 2048;

    // Q B-frags for this wave's 2 q-groups
    int qrow[2];
    bf16x8 qf[2][6];
#pragma unroll
    for (int g = 0; g < 2; ++g) {
        qrow[g] = qt * 128 + g * 64 + wave * 16 + l15;
        const size_t qoff = ((size_t)(b * SEQ + qrow[g])) * QROW + h * 192 + lg * 8;
#pragma unroll
        for (int s = 0; s < 6; ++s) qf[g][s] = *(const bf16x8*)&qbf[qoff + s * 32];
    }

    floatx4 oacc[2][8];
#pragma unroll
    for (int g = 0; g < 2; ++g)
#pragma unroll
        for (int v = 0; v < 8; ++v) oacc[g][v] = 0.f;
    float m_run[2] = {-1e30f, -1e30f}, l_run[2] = {0.f, 0.f};

    // stage K tile [64][192] -> Ks[bufi]; 6 calls/wave; source swizzled so
    // LDS[row][slot] holds channel-group slot^((row>>1)&3)  (row = s*64+tk)
    auto stageK = [&](int bufi, int tt) {
#pragma unroll
        for (int i = 0; i < 6; ++i) {
            const int base = (wave * 6 + i) * 64;
            const int slot = base + lane;
            const int s = slot >> 8, r = slot & 255, tk = r >> 2, ch = r & 3;
            const int chs = ch ^ ((tk >> 1) & 3);
            async_copy16(kb_base + ((size_t)(tt + tk)) * 192 + s * 32 + chs * 8,
                         &Ks[bufi][base * 8]);
        }
    };
    // stage V^T tile [128][64] -> Vs; 4 calls/wave; same swizzle (row = s*128+v)
    auto stageV = [&](int tt) {
#pragma unroll
        for (int i = 0; i < 4; ++i) {
            const int base = (wave * 4 + i) * 64;
            const int slot = base + lane;
            const int s = slot >> 9, r = slot & 511, v = r >> 2, ch = r & 3;
            const int chs = ch ^ ((v >> 1) & 3);
            async_copy16(vt_base + ((size_t)v) * 2048 + tt + s * 32 + chs * 8,
                         &Vs[base * 8]);
        }
    };

    const int kt_max = 2 * qt + 1;
    stageK(0, 0);                    // prologue K(0); drained by first vmcnt(10)

    for (int kt = 0; kt <= kt_max; ++kt) {
        const int t0 = kt * 64;
        const int cur = kt & 1;

        // issue this tile's V and next tile's K (stay in flight across barriers)
        stageV(t0);
        if (kt < kt_max) {
            stageK(cur ^ 1, t0 + 64);
            asm volatile("s_waitcnt vmcnt(10)" ::: "memory");  // drain prev K (oldest)
        } else {
            asm volatile("s_waitcnt vmcnt(4)" ::: "memory");   // no new K issued
        }
        __builtin_amdgcn_s_barrier();    // Ks[cur] visible to all waves

        // S^T[64t][16q] per group: share each K frag across both q-groups
        floatx4 sacc[2][4];
#pragma unroll
        for (int g = 0; g < 2; ++g)
#pragma unroll
            for (int mt = 0; mt < 4; ++mt) sacc[g][mt] = 0.f;
        __builtin_amdgcn_s_setprio(1);
#pragma unroll
        for (int s = 0; s < 6; ++s) {
#pragma unroll
            for (int mt = 0; mt < 4; ++mt) {
                const bf16x8 kf = *(const bf16x8*)&Ks[cur][(s * 64 + mt * 16 + l15) * 32 + lgs * 8];
#pragma unroll
                for (int g = 0; g < 2; ++g)
                    sacc[g][mt] = __builtin_amdgcn_mfma_f32_16x16x32_bf16(
                        kf, qf[g][s], sacc[g][mt], 0, 0, 0);
            }
        }
        __builtin_amdgcn_s_setprio(0);

        // online softmax per q-col; pack P to bf16 regs (pk)
        u16x4 pk[2][4];
#pragma unroll
        for (int g = 0; g < 2; ++g) {
            const bool full = (t0 + 63) <= (qt * 128 + g * 64 + wave * 16);
            float p[16];
            float tmax = -1e30f;
#pragma unroll
            for (int mt = 0; mt < 4; ++mt)
#pragma unroll
                for (int r = 0; r < 4; ++r) {
                    float v = sacc[g][mt][r] * scale;
                    if (!full) {
                        const int tglob = t0 + mt * 16 + lg * 4 + r;
                        v = (tglob <= qrow[g]) ? v : -1e30f;
                    }
                    p[mt * 4 + r] = v;
                    tmax = fmaxf(tmax, v);
                }
            tmax = fmaxf(tmax, __shfl_xor(tmax, 16));
            tmax = fmaxf(tmax, __shfl_xor(tmax, 32));
            // T13 defer-max: if tile max grew by <= 8, keep old m (p <= e^8,
            // safe in bf16/f32) and skip the O-rescale pass entirely.
            const bool defer = __all(tmax <= m_run[g] + 8.0f);
            float alph = 1.0f;
            float mnew = m_run[g];
            if (!defer) {
                mnew = fmaxf(m_run[g], tmax);
                alph = __expf(m_run[g] - mnew);
                m_run[g] = mnew;
            }
            float rsum = 0.f;
#pragma unroll
            for (int k = 0; k < 16; ++k) { p[k] = __expf(p[k] - mnew); rsum += p[k]; }
            rsum += __shfl_xor(rsum, 16);
            rsum += __shfl_xor(rsum, 32);
            if (!defer) {
                l_run[g] = l_run[g] * alph + rsum;
                float af[4];
#pragma unroll
                for (int r = 0; r < 4; ++r) af[r] = __shfl(alph, lg * 4 + r);
#pragma unroll
                for (int vt = 0; vt < 8; ++vt)
#pragma unroll
                    for (int r = 0; r < 4; ++r) oacc[g][vt][r] *= af[r];
            } else {
                l_run[g] += rsum;
            }
#pragma unroll
            for (int mt = 0; mt < 4; ++mt)
#pragma unroll
                for (int r = 0; r < 4; ++r) pk[g][mt][r] = f2bf(p[mt * 4 + r]);
        }

        // Ps round-trip per g (per-wave buffer, in-wave DS ordering) -> pf regs
        bf16x8 pf[2][2];
#pragma unroll
        for (int g = 0; g < 2; ++g) {
#pragma unroll
            for (int mt = 0; mt < 4; ++mt)
                *(u16x4*)&Ps[wave][l15 * 72 + mt * 16 + lg * 4] = pk[g][mt];
#pragma unroll
            for (int s = 0; s < 2; ++s)
                pf[g][s] = *(const bf16x8*)&Ps[wave][l15 * 72 + s * 32 + lg * 8];
        }

        if (kt < kt_max) asm volatile("s_waitcnt vmcnt(6)" ::: "memory");  // drain V, keep K
        else             asm volatile("s_waitcnt vmcnt(0)" ::: "memory");
        __builtin_amdgcn_s_barrier();    // Vs visible to all waves

        // O[g][16q][128v] += P @ V ; V read once, feeds both g
        __builtin_amdgcn_s_setprio(1);
#pragma unroll
        for (int s = 0; s < 2; ++s)
#pragma unroll
            for (int vt = 0; vt < 8; ++vt) {
                const bf16x8 vf = *(const bf16x8*)&Vs[(s * 128 + vt * 16 + l15) * 32 + lgs * 8];
                oacc[0][vt] = __builtin_amdgcn_mfma_f32_16x16x32_bf16(
                    pf[0][s], vf, oacc[0][vt], 0, 0, 0);
                oacc[1][vt] = __builtin_amdgcn_mfma_f32_16x16x32_bf16(
                    pf[1][s], vf, oacc[1][vt], 0, 0, 0);
            }
        __builtin_amdgcn_s_setprio(0);

        // all waves done reading Vs + Ks[cur] before next iter's DMA overwrites
        __builtin_amdgcn_s_barrier();
    }
    // epilogue: divide by l, store bf16
#pragma unroll
    for (int g = 0; g < 2; ++g) {
        float lf[4];
#pragma unroll
        for (int r = 0; r < 4; ++r) lf[r] = 1.0f / __shfl(l_run[g], lg * 4 + r);
#pragma unroll
        for (int vt = 0; vt < 8; ++vt)
#pragma unroll
            for (int r = 0; r < 4; ++r) {
                const int orow = b * SEQ + qt * 128 + g * 64 + wave * 16 + lg * 4 + r;
                att[(size_t)orow * 2048 + h * 128 + vt * 16 + l15] =
                    f2bf(oacc[g][vt][r] * lf[r]);
            }
    }
}

// ---------------------------------------------------------------------------
extern "C" void kernel_launch(void* const* d_in, const int* in_sizes, int n_in,
                              void* d_out, int out_size, void* d_ws, size_t ws_size,
                              hipStream_t stream) {
    const float* x     = (const float*)d_in[0];
    const float* wq    = (const float*)d_in[1];
    const float* wkv_a = (const float*)d_in[2];
    const float* knw   = (const float*)d_in[3];
    const float* wkv_b = (const float*)d_in[4];
    const float* wo    = (const float*)d_in[5];
    const float* fcos  = (const float*)d_in[6];
    const float* fsin  = (const float*)d_in[7];
    float* out = (float*)d_out;

    char* w = (char*)d_ws;
    u16*   x_bf    = (u16*)w;  w += (size_t)NTOK * 2048 * 2;
    u16*   wq_bf   = (u16*)w;  w += (size_t)QROW * 2048 * 2;
    u16*   wkva_bf = (u16*)w;  w += (size_t)640 * 2048 * 2;
    u16*   wkvb_bf = (u16*)w;  w += (size_t)KVBROW * KV_LORA * 2;
    u16*   wo_bf   = (u16*)w;  w += (size_t)2048 * 2048 * 2;
    u16*   q_bf    = (u16*)w;  w += (size_t)NTOK * QROW * 2;
    float* kv_raw  = (float*)w; w += (size_t)NTOK * 640 * 4;
    u16*   kvn_bf  = (u16*)w;  w += (size_t)NTOK * KV_LORA * 2;
    u16*   kbuf    = (u16*)w;  w += (size_t)NH * NB * SEQ * 192 * 2;
    u16*   vT      = (u16*)w;  w += (size_t)NH * NB * 128 * SEQ * 2;
    u16*   att_bf  = (u16*)w;  w += (size_t)NTOK * 2048 * 2;

    const double mm = 0.1 * 1.0 * log(40.0) + 1.0;
    const float scale = (float)((1.0 / sqrt((double)D_QK)) * mm * mm);

    dim3 blk(256);
    cast_all<<<dim3(21760), blk, 0, stream>>>(x, wq, wkv_a, wkv_b, wo,
                                              x_bf, wq_bf, wkva_bf, wkvb_bf, wo_bf);
    gemm_mfma<1><<<dim3(QROW / 128, NTOK / 128), blk, 0, stream>>>(
        x_bf, wq_bf, q_bf, nullptr, nullptr, NTOK, QROW, 2048);
    gemm_mfma<0><<<dim3(640 / 128, NTOK / 128), blk, 0, stream>>>(
        x_bf, wkva_bf, kv_raw, nullptr, nullptr, NTOK, 640, 2048);
    kv_fix<<<dim3(NTOK), blk, 0, stream>>>(kv_raw, knw, fcos, fsin, kvn_bf, kbuf);
    gemm_mfma<2><<<dim3(KVBROW / 128, NTOK / 128), blk, 0, stream>>>(
        kvn_bf, wkvb_bf, nullptr, kbuf, vT, NTOK, KVBROW, KV_LORA);
    attn_mfma<<<dim3(SEQ / 128, NH, NB), blk, 0, stream>>>(q_bf, kbuf, vT, att_bf, scale);
    gemm_mfma<0><<<dim3(2048 / 128, NTOK / 128), blk, 0, stream>>>(
        att_bf, wo_bf, out, nullptr, nullptr, NTOK, 2048, 2048);
}